// Round 1
// baseline (342.888 us; speedup 1.0000x reference)
//
#include <hip/hip_runtime.h>
#include <math.h>

#define BQ 8192
#define HD 1024
#define NE 8

#define BM 128
#define BN 128
#define BK 16

// ---------------- workspace layout (bytes) ----------------
// idx:      int[BQ]      @ 0
// rowlist:  int[BQ]      @ 32768
// count:    int[NE]      @ 65536
// base:     int[NE]      @ 65568
// cursor:   int[NE]      @ 65600
// S:        float[NE]    @ 65632   (sum of routing probs per expert)
// zsum:     float        @ 65664
// cesum:    float        @ 65668
// logits2:  float[BQ*2]  @ 65696   (16B aligned)
// total:    131232 -> memset 131328

#define WS_IDX      0
#define WS_ROWLIST  32768
#define WS_COUNT    65536
#define WS_BASE     65568
#define WS_CURSOR   65600
#define WS_S        65632
#define WS_ZSUM     65664
#define WS_CESUM    65668
#define WS_LOGITS2  65696
#define WS_TOTAL    131328

__device__ __forceinline__ float gelu_exact(float v) {
    return 0.5f * v * (1.0f + erff(v * 0.70710678118654752440f));
}

// ---------------- router ----------------
// grid 256 blocks x 256 threads (4 waves). Each wave handles 8 rows.
__global__ __launch_bounds__(256) void router_kernel(
    const float* __restrict__ x, const float* __restrict__ gate_w,
    int* __restrict__ idx, int* __restrict__ count,
    float* __restrict__ S, float* __restrict__ zsum)
{
    __shared__ float gw[NE * HD];   // 32 KB
    __shared__ float sS[NE];
    __shared__ float sZ;
    __shared__ int   sC[NE];

    int tid = threadIdx.x;
    for (int i = tid * 4; i < NE * HD; i += 256 * 4) {
        *(float4*)(gw + i) = *(const float4*)(gate_w + i);
    }
    if (tid < NE) { sS[tid] = 0.f; sC[tid] = 0; }
    if (tid == 0) sZ = 0.f;
    __syncthreads();

    int wave = tid >> 6, lane = tid & 63;
    float accS[NE];
    int   accC[NE];
    #pragma unroll
    for (int e = 0; e < NE; e++) { accS[e] = 0.f; accC[e] = 0; }
    float accZ = 0.f;

    int waveId = blockIdx.x * 4 + wave;     // 0..1023
    for (int r = waveId; r < BQ; r += gridDim.x * 4) {
        const float* xr = x + (size_t)r * HD;
        float acc[NE];
        #pragma unroll
        for (int e = 0; e < NE; e++) acc[e] = 0.f;
        #pragma unroll
        for (int it = 0; it < HD / 256; it++) {
            int k = lane * 4 + it * 256;
            float4 xv = *(const float4*)(xr + k);
            #pragma unroll
            for (int e = 0; e < NE; e++) {
                const float* g = gw + e * HD + k;
                acc[e] += xv.x * g[0] + xv.y * g[1] + xv.z * g[2] + xv.w * g[3];
            }
        }
        #pragma unroll
        for (int e = 0; e < NE; e++) {
            #pragma unroll
            for (int off = 32; off > 0; off >>= 1)
                acc[e] += __shfl_xor(acc[e], off);
        }
        if (lane == 0) {
            float m = acc[0]; int bi = 0;
            #pragma unroll
            for (int e = 1; e < NE; e++) if (acc[e] > m) { m = acc[e]; bi = e; }
            float se = 0.f, ex[NE];
            #pragma unroll
            for (int e = 0; e < NE; e++) { ex[e] = expf(acc[e] - m); se += ex[e]; }
            float inv = 1.f / se;
            #pragma unroll
            for (int e = 0; e < NE; e++) accS[e] += ex[e] * inv;
            float lse = m + logf(se);
            accZ += lse * lse;
            accC[bi] += 1;
            idx[r] = bi;
        }
    }
    if (lane == 0) {
        #pragma unroll
        for (int e = 0; e < NE; e++) {
            atomicAdd(&sS[e], accS[e]);
            if (accC[e]) atomicAdd(&sC[e], accC[e]);
        }
        atomicAdd(&sZ, accZ);
    }
    __syncthreads();
    if (tid < NE) {
        atomicAdd(&S[tid], sS[tid]);
        atomicAdd(&count[tid], sC[tid]);
    }
    if (tid == 0) atomicAdd(zsum, sZ);
}

// ---------------- prefix ----------------
__global__ void prefix_kernel(const int* __restrict__ count,
                              int* __restrict__ base, int* __restrict__ cursor)
{
    if (threadIdx.x == 0 && blockIdx.x == 0) {
        int acc = 0;
        for (int e = 0; e < NE; e++) { base[e] = acc; cursor[e] = acc; acc += count[e]; }
    }
}

// ---------------- scatter / compaction ----------------
__global__ __launch_bounds__(256) void scatter_kernel(
    const int* __restrict__ idx, int* __restrict__ cursor, int* __restrict__ rowlist)
{
    __shared__ int loc[NE];
    __shared__ int basev[NE];
    int tid = threadIdx.x;
    int r = blockIdx.x * 256 + tid;
    if (tid < NE) loc[tid] = 0;
    __syncthreads();
    int e = idx[r];
    int my = atomicAdd(&loc[e], 1);
    __syncthreads();
    if (tid < NE) basev[tid] = atomicAdd(&cursor[tid], loc[tid]);
    __syncthreads();
    rowlist[basev[e] + my] = r;
}

// ---------------- fused expert GEMM + bias + gelu + w2 reduce ----------------
// grid (HD/BN=8, 24, NE=8), 256 threads.
__global__ __launch_bounds__(256) void expert_gemm_kernel(
    const float* __restrict__ x, const float* __restrict__ w1,
    const float* __restrict__ b1, const float* __restrict__ w2,
    const int* __restrict__ rowlist, const int* __restrict__ base,
    const int* __restrict__ count, float* __restrict__ logits2)
{
    int e = blockIdx.z;
    int cnt = count[e];
    int rt = blockIdx.y;
    if (rt * BM >= cnt) return;
    int n0 = blockIdx.x * BN;

    __shared__ float AsT[BK][BM + 4];   // [16][132]
    __shared__ float Bs[BK][BN + 4];    // [16][132]
    __shared__ int rows_s[BM];

    int tid = threadIdx.x;
    if (tid < BM) {
        int p = rt * BM + tid;
        rows_s[tid] = (p < cnt) ? rowlist[base[e] + p] : -1;
    }
    __syncthreads();

    int tx = tid & 15, ty = tid >> 4;
    float acc[8][8];
    #pragma unroll
    for (int i = 0; i < 8; i++)
        #pragma unroll
        for (int j = 0; j < 8; j++) acc[i][j] = 0.f;

    const float* w1e = w1 + (size_t)e * HD * HD;

    for (int k0 = 0; k0 < HD; k0 += BK) {
        // stage A (gathered rows), transposed into AsT
        #pragma unroll
        for (int s = 0; s < 2; s++) {
            int li = tid + s * 256;     // float4 index 0..511
            int r = li >> 2;            // row in tile
            int q = li & 3;             // which float4 in the 16-wide k slice
            int row = rows_s[r];
            float4 v = make_float4(0.f, 0.f, 0.f, 0.f);
            if (row >= 0) v = *(const float4*)(x + (size_t)row * HD + k0 + q * 4);
            AsT[q * 4 + 0][r] = v.x;
            AsT[q * 4 + 1][r] = v.y;
            AsT[q * 4 + 2][r] = v.z;
            AsT[q * 4 + 3][r] = v.w;
        }
        // stage B
        #pragma unroll
        for (int s = 0; s < 2; s++) {
            int li = tid + s * 256;     // float4 index 0..511
            int kk = li >> 5;           // 32 float4 per k row
            int nq = li & 31;
            float4 v = *(const float4*)(w1e + (size_t)(k0 + kk) * HD + n0 + nq * 4);
            *(float4*)(&Bs[kk][nq * 4]) = v;
        }
        __syncthreads();
        #pragma unroll
        for (int kk = 0; kk < BK; kk++) {
            float av[8], bv[8];
            *(float4*)&av[0] = *(const float4*)(&AsT[kk][ty * 4]);
            *(float4*)&av[4] = *(const float4*)(&AsT[kk][ty * 4 + 64]);
            *(float4*)&bv[0] = *(const float4*)(&Bs[kk][tx * 4]);
            *(float4*)&bv[4] = *(const float4*)(&Bs[kk][tx * 4 + 64]);
            #pragma unroll
            for (int i = 0; i < 8; i++)
                #pragma unroll
                for (int j = 0; j < 8; j++)
                    acc[i][j] += av[i] * bv[j];
        }
        __syncthreads();
    }

    // epilogue: bias + gelu + w2 partial reduce + atomic into logits2
    int cj[8];
    float b1r[8], w20[8], w21[8];
    #pragma unroll
    for (int j = 0; j < 8; j++) {
        cj[j] = n0 + tx * 4 + (j & 3) + ((j >> 2) * 64);
        b1r[j] = b1[e * HD + cj[j]];
        w20[j] = w2[((size_t)e * HD + cj[j]) * 2 + 0];
        w21[j] = w2[((size_t)e * HD + cj[j]) * 2 + 1];
    }
    #pragma unroll
    for (int i = 0; i < 8; i++) {
        int r = ty * 4 + (i & 3) + ((i >> 2) * 64);
        int row = rows_s[r];
        float s0 = 0.f, s1 = 0.f;
        #pragma unroll
        for (int j = 0; j < 8; j++) {
            float h = gelu_exact(acc[i][j] + b1r[j]);
            s0 += h * w20[j];
            s1 += h * w21[j];
        }
        #pragma unroll
        for (int off = 1; off < 16; off <<= 1) {
            s0 += __shfl_xor(s0, off);
            s1 += __shfl_xor(s1, off);
        }
        if (tx == 0 && row >= 0) {
            atomicAdd(&logits2[row * 2 + 0], s0);
            atomicAdd(&logits2[row * 2 + 1], s1);
        }
    }
}

// ---------------- CE over (softmaxed) expert outputs ----------------
__global__ __launch_bounds__(256) void ce_kernel(
    const float* __restrict__ logits2, const float* __restrict__ b2,
    const int* __restrict__ idx, const int* __restrict__ label,
    float* __restrict__ cesum)
{
    __shared__ float red[4];
    int tid = threadIdx.x;
    int r = blockIdx.x * 256 + tid;
    int e = idx[r];
    float l0 = logits2[r * 2 + 0] + b2[e * 2 + 0];
    float l1 = logits2[r * 2 + 1] + b2[e * 2 + 1];
    // probs = softmax(l0,l1)
    float m = fmaxf(l0, l1);
    float e0 = expf(l0 - m), e1 = expf(l1 - m);
    float inv = 1.f / (e0 + e1);
    float p0 = e0 * inv, p1 = e1 * inv;
    // ce = -log_softmax(probs)[label]   (weight == 1 exactly)
    float m2 = fmaxf(p0, p1);
    float z = m2 + logf(expf(p0 - m2) + expf(p1 - m2));
    float lp = ((label[r] == 0) ? p0 : p1) - z;
    float ce = -lp;

    int lane = tid & 63, wave = tid >> 6;
    #pragma unroll
    for (int off = 32; off > 0; off >>= 1) ce += __shfl_xor(ce, off);
    if (lane == 0) red[wave] = ce;
    __syncthreads();
    if (tid == 0) atomicAdd(cesum, red[0] + red[1] + red[2] + red[3]);
}

// ---------------- finalize ----------------
__global__ void finalize_kernel(const float* __restrict__ S, const int* __restrict__ count,
                                const float* __restrict__ zsum, const float* __restrict__ cesum,
                                float* __restrict__ out)
{
    if (threadIdx.x == 0 && blockIdx.x == 0) {
        float bal = 0.f;
        for (int e = 0; e < NE; e++) bal += S[e] * (float)count[e];
        bal *= (float)NE / ((float)BQ * (float)BQ);
        out[0] = cesum[0] / (float)BQ + 0.01f * bal + 0.001f * (zsum[0] / (float)BQ);
    }
}

extern "C" void kernel_launch(void* const* d_in, const int* in_sizes, int n_in,
                              void* d_out, int out_size, void* d_ws, size_t ws_size,
                              hipStream_t stream) {
    const float* x      = (const float*)d_in[0];
    const int*   label  = (const int*)d_in[1];
    const float* gate_w = (const float*)d_in[2];
    const float* w1     = (const float*)d_in[3];
    const float* b1     = (const float*)d_in[4];
    const float* w2     = (const float*)d_in[5];
    const float* b2     = (const float*)d_in[6];
    float* out = (float*)d_out;

    char* ws = (char*)d_ws;
    int*   idx     = (int*)(ws + WS_IDX);
    int*   rowlist = (int*)(ws + WS_ROWLIST);
    int*   count   = (int*)(ws + WS_COUNT);
    int*   base    = (int*)(ws + WS_BASE);
    int*   cursor  = (int*)(ws + WS_CURSOR);
    float* S       = (float*)(ws + WS_S);
    float* zsum    = (float*)(ws + WS_ZSUM);
    float* cesum   = (float*)(ws + WS_CESUM);
    float* logits2 = (float*)(ws + WS_LOGITS2);

    hipMemsetAsync(d_ws, 0, WS_TOTAL, stream);

    router_kernel<<<256, 256, 0, stream>>>(x, gate_w, idx, count, S, zsum);
    prefix_kernel<<<1, 64, 0, stream>>>(count, base, cursor);
    scatter_kernel<<<BQ / 256, 256, 0, stream>>>(idx, cursor, rowlist);
    expert_gemm_kernel<<<dim3(HD / BN, 24, NE), 256, 0, stream>>>(
        x, w1, b1, w2, rowlist, base, count, logits2);
    ce_kernel<<<BQ / 256, 256, 0, stream>>>(logits2, b2, idx, label, cesum);
    finalize_kernel<<<1, 64, 0, stream>>>(S, count, zsum, cesum, out);
}

// Round 2
// 101.439 us; speedup vs baseline: 3.3802x; 3.3802x over previous
//
#include <hip/hip_runtime.h>
#include <math.h>

#define BQ 8192
#define HD 1024
#define NE 8

#define BM 128
#define BN 128
#define BK 32

// ---------------- workspace layout (bytes) ----------------
#define WS_IDX      0           // int[BQ]
#define WS_ROWLIST  32768       // int[BQ]
#define WS_COUNT    65536       // int[NE]
#define WS_BASE     65568       // int[NE]
#define WS_CURSOR   65600       // int[NE]
#define WS_S        65632       // float[NE]
#define WS_ZSUM     65664       // float
#define WS_CESUM    65668       // float
#define WS_ZPAD     65696       // 64B zero scratch (for padded A rows)
#define WS_LOGITS2  65792       // float[BQ*2] = 65536B
#define WS_HEAD     131328      // memset size
#define WS_XB       131328      // bf16 x [BQ][HD] = 16777216B
#define WS_W1T      16908544    // bf16 w1^T [NE][HD(n)][HD(k)] = 16777216B

using f32x4  = __attribute__((ext_vector_type(4))) float;
using bf16x8 = __attribute__((ext_vector_type(8))) __bf16;

__device__ __forceinline__ float gelu_exact(float v) {
    return 0.5f * v * (1.0f + erff(v * 0.70710678118654752440f));
}

__device__ __forceinline__ unsigned short f2bf(float f) {
    union { float f; unsigned int u; } v; v.f = f;
    unsigned int u = v.u;
    unsigned int r = (u + 0x7FFFu + ((u >> 16) & 1u)) >> 16;
    return (unsigned short)r;
}

__device__ __forceinline__ void gll16(const void* g, void* l) {
    __builtin_amdgcn_global_load_lds((const __attribute__((address_space(1))) void*)g,
                                     (__attribute__((address_space(3))) void*)l, 16, 0, 0);
}

// ---------------- router + x->bf16 conversion ----------------
__global__ __launch_bounds__(256) void router_kernel(
    const float* __restrict__ x, const float* __restrict__ gate_w,
    int* __restrict__ idx, int* __restrict__ count,
    float* __restrict__ S, float* __restrict__ zsum,
    unsigned short* __restrict__ xb)
{
    __shared__ float gw[NE * HD];   // 32 KB
    __shared__ float sS[NE];
    __shared__ float sZ;
    __shared__ int   sC[NE];

    int tid = threadIdx.x;
    for (int i = tid * 4; i < NE * HD; i += 256 * 4) {
        *(float4*)(gw + i) = *(const float4*)(gate_w + i);
    }
    if (tid < NE) { sS[tid] = 0.f; sC[tid] = 0; }
    if (tid == 0) sZ = 0.f;
    __syncthreads();

    int wave = tid >> 6, lane = tid & 63;
    float accS[NE];
    int   accC[NE];
    #pragma unroll
    for (int e = 0; e < NE; e++) { accS[e] = 0.f; accC[e] = 0; }
    float accZ = 0.f;

    int waveId = blockIdx.x * 4 + wave;     // 0..1023
    for (int r = waveId; r < BQ; r += gridDim.x * 4) {
        const float* xr = x + (size_t)r * HD;
        float acc[NE];
        #pragma unroll
        for (int e = 0; e < NE; e++) acc[e] = 0.f;
        #pragma unroll
        for (int it = 0; it < HD / 256; it++) {
            int k = lane * 4 + it * 256;
            float4 xv = *(const float4*)(xr + k);
            // fused bf16 conversion write
            ushort4 o;
            o.x = f2bf(xv.x); o.y = f2bf(xv.y); o.z = f2bf(xv.z); o.w = f2bf(xv.w);
            *(ushort4*)(xb + (size_t)r * HD + k) = o;
            #pragma unroll
            for (int e = 0; e < NE; e++) {
                const float* g = gw + e * HD + k;
                acc[e] += xv.x * g[0] + xv.y * g[1] + xv.z * g[2] + xv.w * g[3];
            }
        }
        #pragma unroll
        for (int e = 0; e < NE; e++) {
            #pragma unroll
            for (int off = 32; off > 0; off >>= 1)
                acc[e] += __shfl_xor(acc[e], off);
        }
        if (lane == 0) {
            float m = acc[0]; int bi = 0;
            #pragma unroll
            for (int e = 1; e < NE; e++) if (acc[e] > m) { m = acc[e]; bi = e; }
            float se = 0.f, ex[NE];
            #pragma unroll
            for (int e = 0; e < NE; e++) { ex[e] = expf(acc[e] - m); se += ex[e]; }
            float inv = 1.f / se;
            #pragma unroll
            for (int e = 0; e < NE; e++) accS[e] += ex[e] * inv;
            float lse = m + logf(se);
            accZ += lse * lse;
            accC[bi] += 1;
            idx[r] = bi;
        }
    }
    if (lane == 0) {
        #pragma unroll
        for (int e = 0; e < NE; e++) {
            atomicAdd(&sS[e], accS[e]);
            if (accC[e]) atomicAdd(&sC[e], accC[e]);
        }
        atomicAdd(&sZ, accZ);
    }
    __syncthreads();
    if (tid < NE) {
        atomicAdd(&S[tid], sS[tid]);
        atomicAdd(&count[tid], sC[tid]);
    }
    if (tid == 0) atomicAdd(zsum, sZ);
}

// ---------------- w1 fp32 [e][k][n] -> bf16 [e][n][k] ----------------
// 64x64 tiles, grid (16,16,8), 256 threads
__global__ __launch_bounds__(256) void w1_transpose_kernel(
    const float* __restrict__ w1, unsigned short* __restrict__ w1t)
{
    __shared__ unsigned short lt[64][72];   // [n][k], padded
    int t = threadIdx.x;
    int e = blockIdx.z;
    int k0 = blockIdx.y * 64, n0 = blockIdx.x * 64;
    const float* src = w1 + ((size_t)e << 20) + (size_t)k0 * HD + n0;
    #pragma unroll
    for (int s = 0; s < 4; s++) {
        int q = t + s * 256;        // float4 index within 64x64 tile
        int kk = q >> 4;            // 16 float4 per k-row
        int n4 = q & 15;
        float4 v = *(const float4*)(src + (size_t)kk * HD + n4 * 4);
        lt[n4 * 4 + 0][kk] = f2bf(v.x);
        lt[n4 * 4 + 1][kk] = f2bf(v.y);
        lt[n4 * 4 + 2][kk] = f2bf(v.z);
        lt[n4 * 4 + 3][kk] = f2bf(v.w);
    }
    __syncthreads();
    unsigned short* dst = w1t + ((size_t)e << 20) + (size_t)n0 * HD + k0;
    #pragma unroll
    for (int s = 0; s < 4; s++) {
        int q = t + s * 256;        // ushort4 index within 64x64 out tile
        int nn = q >> 4;
        int kq = q & 15;
        *(ushort4*)(dst + (size_t)nn * HD + kq * 4) = *(ushort4*)&lt[nn][kq * 4];
    }
}

// ---------------- prefix ----------------
__global__ void prefix_kernel(const int* __restrict__ count,
                              int* __restrict__ base, int* __restrict__ cursor)
{
    if (threadIdx.x == 0 && blockIdx.x == 0) {
        int acc = 0;
        for (int e = 0; e < NE; e++) { base[e] = acc; cursor[e] = acc; acc += count[e]; }
    }
}

// ---------------- scatter / compaction ----------------
__global__ __launch_bounds__(256) void scatter_kernel(
    const int* __restrict__ idx, int* __restrict__ cursor, int* __restrict__ rowlist)
{
    __shared__ int loc[NE];
    __shared__ int basev[NE];
    int tid = threadIdx.x;
    int r = blockIdx.x * 256 + tid;
    if (tid < NE) loc[tid] = 0;
    __syncthreads();
    int e = idx[r];
    int my = atomicAdd(&loc[e], 1);
    __syncthreads();
    if (tid < NE) basev[tid] = atomicAdd(&cursor[tid], loc[tid]);
    __syncthreads();
    rowlist[basev[e] + my] = r;
}

// ---------------- MFMA expert GEMM + bias + gelu + w2 reduce ----------------
// grid (HD/BN=8, 24, NE=8), 256 threads = 4 waves (2x2), each wave 64x64 out.
__global__ __launch_bounds__(256) void expert_gemm_kernel(
    const unsigned short* __restrict__ xb, const unsigned short* __restrict__ w1t,
    const float* __restrict__ b1, const float* __restrict__ w2,
    const int* __restrict__ rowlist, const int* __restrict__ base,
    const int* __restrict__ count, float* __restrict__ logits2,
    const char* __restrict__ zeropad)
{
    int e = blockIdx.z;
    int cnt = count[e];
    int rt = blockIdx.y;
    if (rt * BM >= cnt) return;
    int n0 = blockIdx.x * BN;

    __shared__ __align__(16) char Ab[BM * BK * 2];   // [m][k] bf16, 64B rows
    __shared__ __align__(16) char Bb[BN * BK * 2];   // [n][k] bf16, 64B rows
    __shared__ int rows_s[BM];

    int t = threadIdx.x;
    if (t < BM) {
        int p = rt * BM + t;
        rows_s[t] = (p < cnt) ? rowlist[base[e] + p] : -1;
    }
    __syncthreads();

    // staging source addresses (per thread, 16B each, 2 segments per tile)
    int kb = (t & 3) * 16;          // byte offset within 64B k-row
    const char* xbp = (const char*)xb;
    const char* srcA[2]; int stepA[2];
    #pragma unroll
    for (int s = 0; s < 2; s++) {
        int m = (t >> 2) + 64 * s;
        int row = rows_s[m];
        if (row >= 0) { srcA[s] = xbp + (size_t)row * (HD * 2) + kb; stepA[s] = BK * 2; }
        else          { srcA[s] = zeropad + kb; stepA[s] = 0; }
    }
    const char* w1tp = (const char*)w1t + ((size_t)e << 21);
    const char* srcB[2];
    #pragma unroll
    for (int s = 0; s < 2; s++) {
        int n = (t >> 2) + 64 * s;
        srcB[s] = w1tp + (size_t)(n0 + n) * (HD * 2) + kb;
    }

    int lane = t & 63, wid = t >> 6;
    int wr = wid >> 1, wc = wid & 1;
    int h = lane >> 4, r = lane & 15;
    const char* Abase = Ab + (wr * 64 + r) * (BK * 2) + h * 16;
    const char* Bbase = Bb + (wc * 64 + r) * (BK * 2) + h * 16;

    f32x4 acc[4][4];
    #pragma unroll
    for (int i = 0; i < 4; i++)
        #pragma unroll
        for (int j = 0; j < 4; j++) acc[i][j] = (f32x4)(0.f);

    for (int k0 = 0; k0 < HD; k0 += BK) {
        gll16(srcA[0], Ab + t * 16);
        gll16(srcA[1], Ab + t * 16 + 4096);
        gll16(srcB[0], Bb + t * 16);
        gll16(srcB[1], Bb + t * 16 + 4096);
        srcA[0] += stepA[0]; srcA[1] += stepA[1];
        srcB[0] += BK * 2;   srcB[1] += BK * 2;
        __syncthreads();

        bf16x8 af[4], bf[4];
        #pragma unroll
        for (int f = 0; f < 4; f++) {
            af[f] = *(const bf16x8*)(Abase + f * 16 * (BK * 2));
            bf[f] = *(const bf16x8*)(Bbase + f * 16 * (BK * 2));
        }
        #pragma unroll
        for (int i = 0; i < 4; i++)
            #pragma unroll
            for (int j = 0; j < 4; j++)
                acc[i][j] = __builtin_amdgcn_mfma_f32_16x16x32_bf16(af[i], bf[j], acc[i][j], 0, 0, 0);
        __syncthreads();
    }

    // epilogue: bias + gelu + w2 partial dot + reduce over 16 lanes (cols)
    float b1v[4], w20v[4], w21v[4];
    #pragma unroll
    for (int j = 0; j < 4; j++) {
        int col = n0 + wc * 64 + j * 16 + r;
        b1v[j]  = b1[e * HD + col];
        w20v[j] = w2[((size_t)e * HD + col) * 2 + 0];
        w21v[j] = w2[((size_t)e * HD + col) * 2 + 1];
    }
    #pragma unroll
    for (int i = 0; i < 4; i++) {
        #pragma unroll
        for (int reg = 0; reg < 4; reg++) {
            float s0 = 0.f, s1 = 0.f;
            #pragma unroll
            for (int j = 0; j < 4; j++) {
                float hv = gelu_exact(acc[i][j][reg] + b1v[j]);
                s0 += hv * w20v[j];
                s1 += hv * w21v[j];
            }
            #pragma unroll
            for (int off = 1; off < 16; off <<= 1) {
                s0 += __shfl_xor(s0, off);
                s1 += __shfl_xor(s1, off);
            }
            if (r == 0) {
                int lm = wr * 64 + i * 16 + 4 * h + reg;
                int row = rows_s[lm];
                if (row >= 0) {
                    atomicAdd(&logits2[row * 2 + 0], s0);
                    atomicAdd(&logits2[row * 2 + 1], s1);
                }
            }
        }
    }
}

// ---------------- CE over (softmaxed) expert outputs ----------------
__global__ __launch_bounds__(256) void ce_kernel(
    const float* __restrict__ logits2, const float* __restrict__ b2,
    const int* __restrict__ idx, const int* __restrict__ label,
    float* __restrict__ cesum)
{
    __shared__ float red[4];
    int tid = threadIdx.x;
    int r = blockIdx.x * 256 + tid;
    int e = idx[r];
    float l0 = logits2[r * 2 + 0] + b2[e * 2 + 0];
    float l1 = logits2[r * 2 + 1] + b2[e * 2 + 1];
    float m = fmaxf(l0, l1);
    float e0 = expf(l0 - m), e1 = expf(l1 - m);
    float inv = 1.f / (e0 + e1);
    float p0 = e0 * inv, p1 = e1 * inv;
    float m2 = fmaxf(p0, p1);
    float z = m2 + logf(expf(p0 - m2) + expf(p1 - m2));
    float lp = ((label[r] == 0) ? p0 : p1) - z;
    float ce = -lp;

    int lane = tid & 63, wave = tid >> 6;
    #pragma unroll
    for (int off = 32; off > 0; off >>= 1) ce += __shfl_xor(ce, off);
    if (lane == 0) red[wave] = ce;
    __syncthreads();
    if (tid == 0) atomicAdd(cesum, red[0] + red[1] + red[2] + red[3]);
}

// ---------------- finalize ----------------
__global__ void finalize_kernel(const float* __restrict__ S, const int* __restrict__ count,
                                const float* __restrict__ zsum, const float* __restrict__ cesum,
                                float* __restrict__ out)
{
    if (threadIdx.x == 0 && blockIdx.x == 0) {
        float bal = 0.f;
        for (int e = 0; e < NE; e++) bal += S[e] * (float)count[e];
        bal *= (float)NE / ((float)BQ * (float)BQ);
        out[0] = cesum[0] / (float)BQ + 0.01f * bal + 0.001f * (zsum[0] / (float)BQ);
    }
}

extern "C" void kernel_launch(void* const* d_in, const int* in_sizes, int n_in,
                              void* d_out, int out_size, void* d_ws, size_t ws_size,
                              hipStream_t stream) {
    const float* x      = (const float*)d_in[0];
    const int*   label  = (const int*)d_in[1];
    const float* gate_w = (const float*)d_in[2];
    const float* w1     = (const float*)d_in[3];
    const float* b1     = (const float*)d_in[4];
    const float* w2     = (const float*)d_in[5];
    const float* b2     = (const float*)d_in[6];
    float* out = (float*)d_out;

    char* ws = (char*)d_ws;
    int*   idx     = (int*)(ws + WS_IDX);
    int*   rowlist = (int*)(ws + WS_ROWLIST);
    int*   count   = (int*)(ws + WS_COUNT);
    int*   base    = (int*)(ws + WS_BASE);
    int*   cursor  = (int*)(ws + WS_CURSOR);
    float* S       = (float*)(ws + WS_S);
    float* zsum    = (float*)(ws + WS_ZSUM);
    float* cesum   = (float*)(ws + WS_CESUM);
    float* logits2 = (float*)(ws + WS_LOGITS2);
    const char* zeropad = (const char*)(ws + WS_ZPAD);
    unsigned short* xb  = (unsigned short*)(ws + WS_XB);
    unsigned short* w1t = (unsigned short*)(ws + WS_W1T);

    hipMemsetAsync(d_ws, 0, WS_HEAD, stream);

    router_kernel<<<256, 256, 0, stream>>>(x, gate_w, idx, count, S, zsum, xb);
    w1_transpose_kernel<<<dim3(16, 16, 8), 256, 0, stream>>>(w1, w1t);
    prefix_kernel<<<1, 64, 0, stream>>>(count, base, cursor);
    scatter_kernel<<<BQ / 256, 256, 0, stream>>>(idx, cursor, rowlist);
    expert_gemm_kernel<<<dim3(HD / BN, 24, NE), 256, 0, stream>>>(
        xb, w1t, b1, w2, rowlist, base, count, logits2, zeropad);
    ce_kernel<<<BQ / 256, 256, 0, stream>>>(logits2, b2, idx, label, cesum);
    finalize_kernel<<<1, 64, 0, stream>>>(S, count, zsum, cesum, out);
}